// Round 1
// baseline (423.976 us; speedup 1.0000x reference)
//
#include <hip/hip_runtime.h>
#include <math.h>

#define MM 1024      // checks
#define NN 2048      // vars
#define BB 128       // batch
#define TT 5         // iterations
#define EE 6144      // edges

typedef __bf16 bf16x8 __attribute__((ext_vector_type(8)));
typedef __bf16 bf16x4 __attribute__((ext_vector_type(4)));
typedef short  s16x4  __attribute__((ext_vector_type(4)));
typedef float  f32x4  __attribute__((ext_vector_type(4)));
typedef unsigned int u32x4 __attribute__((ext_vector_type(4)));

// prepped weight sizes (bf16 elements)
#define CHK_W_ELEMS 22272   // 24 x32-frags (512) + 39 x16-frags (256)
#define CHK_L2_OFF  12288
#define VAR_W_ELEMS 7168    // 7 x32-frags + 14 x16-frags
#define VAR_L2_OFF  3584

// Abramowitz-Stegun 7.1.26 erf (|eps| < 1.5e-7)
__device__ __forceinline__ float gelu_fast(float x) {
    float xe = x * 0.70710678118654752f;
    float ax = fabsf(xe);
    float t  = __builtin_amdgcn_rcpf(1.0f + 0.3275911f * ax);
    float p  = t * (0.254829592f + t * (-0.284496736f + t * (1.421413741f +
               t * (-1.453152027f + t * 1.061405429f))));
    float er = 1.0f - p * __expf(-xe * xe);
    er = copysignf(er, xe);
    return 0.5f * x * (1.0f + er);
}

// 16x16x16 bf16 MFMA: B-operand layout == C/D layout of a prior MFMA ->
// register-chained layer2 (no LDS transpose on the critical path).
__device__ __forceinline__ f32x4 mfma16(bf16x4 a, bf16x4 b, f32x4 c) {
#if __has_builtin(__builtin_amdgcn_mfma_f32_16x16x16bf16_1k)
    return __builtin_amdgcn_mfma_f32_16x16x16bf16_1k(
        __builtin_bit_cast(s16x4, a), __builtin_bit_cast(s16x4, b), c, 0, 0, 0);
#else
    f32x4 d;
    asm volatile("v_mfma_f32_16x16x16_bf16 %0, %1, %2, %3\n\ts_nop 4"
                 : "=v"(d) : "v"(a), "v"(b), "v"(c));
    return d;
#endif
}

// wave-private LDS fence (DS ops in-order per wave)
__device__ __forceinline__ void wave_lds_fence() {
    asm volatile("s_waitcnt lgkmcnt(0)" ::: "memory");
}

// ---------------------------------------------------------------------------
// prep_fused: one grid does (a) chk weight pack, (b) var weight pack,
// (c) syndrome sign transpose, (d) v2c init.
//
// Weight pack strategy (replaces scalar strided gathers of the old prep_all):
//   stage the whole per-task fp32 matrix into LDS with coalesced float4
//   streams, then emit bf16 fragments whose STORE index is linear in the
//   chunk id (perfectly coalesced), taking the scatter on the LDS side.
// Block types by blockIdx.x:
//   [0,1024)      chk pack, one m per block   (LDS 74.7 KB)
//   [1024,3072)   var pack, one nv per block
//   [3072,3584)   sgnT
//   [3584,6656)   v2c init
// ---------------------------------------------------------------------------
#define PREP_GRID (1024 + 2048 + 512 + 3072)

__global__ __launch_bounds__(256)
void prep_fused(const float* __restrict__ cw1, const float* __restrict__ cb1,
                const float* __restrict__ cw2, const float* __restrict__ cb2,
                const float* __restrict__ vw1, const float* __restrict__ vb1,
                const float* __restrict__ vw2, const float* __restrict__ vb2,
                const int* __restrict__ synd, const float* __restrict__ prior,
                __bf16* __restrict__ wchk, __bf16* __restrict__ wvar,
                float* __restrict__ sgnT, __bf16* __restrict__ v2c)
{
    const int bid = blockIdx.x;
    const int tid = threadIdx.x;

    // union workspace: chk uses w1[0,9216) w2[9216,18432) b1[18432,18624) b2[18624,18672)
    //                  var uses w1[0,2500)  w2[2500,5000)  b1[5000,5100)   b2[5100,5125)
    __shared__ __align__(16) float s[18672];   // 74.7 KB

    if (bid < 1024) {
        // ---------------- chk weight pack ----------------
        const int m = bid;
        {
            const float4* g1 = (const float4*)(cw1 + (size_t)m * 9216);
            const float4* g2 = (const float4*)(cw2 + (size_t)m * 9216);
            float4* s4 = (float4*)s;
            #pragma unroll
            for (int it = 0; it < 9; ++it) s4[it * 256 + tid] = g1[it * 256 + tid];
            #pragma unroll
            for (int it = 0; it < 9; ++it) s4[2304 + it * 256 + tid] = g2[it * 256 + tid];
            if (tid < 192) s[18432 + tid] = cb1[(size_t)m * 192 + tid];
            if (tid < 48)  s[18624 + tid] = cb2[(size_t)m * 48 + tid];
        }
        __syncthreads();

        __bf16* dst = wchk + (size_t)m * CHK_W_ELEMS;

        // L1 frags: 24 frags x 64 lanes x bf16x8; chunk i -> dst[i*8] (linear)
        #pragma unroll
        for (int it = 0; it < 6; ++it) {
            int i = it * 256 + tid;
            int l = i & 63, f = i >> 6;
            int mt = f >> 1, kt = f & 1, q = l >> 4, c = l & 15;
            int h = mt * 16 + c;
            bf16x8 v;
            #pragma unroll
            for (int j = 0; j < 8; ++j) {
                int k  = kt * 32 + q * 8 + j;
                int kc = min(k, 47);
                float wv = s[kc * 192 + h];
                float x  = (k < 48) ? wv : ((k == 48) ? s[18432 + h] : 0.0f);
                v[j] = (__bf16)x;
            }
            *(bf16x8*)(dst + i * 8) = v;
        }
        // L2 frags: 39 frags x 64 lanes x bf16x4; chunk i -> dst[L2 + i*4] (linear)
        #pragma unroll
        for (int it = 0; it < 10; ++it) {
            int i = it * 256 + tid;
            if (i < 2496) {
                int l = i & 63, f = i >> 6;
                int ks = f / 3, mt = f - ks * 3;
                int q = l >> 4, c = l & 15, o = mt * 16 + c;
                bf16x4 v;
                #pragma unroll
                for (int r = 0; r < 4; ++r) {
                    int k  = ks * 16 + q * 4 + r;
                    int kc = min(k, 191);
                    float wv = s[9216 + kc * 48 + o];
                    float x  = (k < 192) ? wv : ((k == 192) ? s[18624 + o] : 0.0f);
                    v[r] = (__bf16)x;
                }
                *(bf16x4*)(dst + CHK_L2_OFF + i * 4) = v;
            }
        }
    } else if (bid < 3072) {
        // ---------------- var weight pack ----------------
        const int nv = bid - 1024;
        {
            const float4* g1 = (const float4*)(vw1 + (size_t)nv * 2500);
            const float4* g2 = (const float4*)(vw2 + (size_t)nv * 2500);
            float4* s4 = (float4*)s;
            #pragma unroll
            for (int it = 0; it < 3; ++it) {
                int i = it * 256 + tid;
                if (i < 625) s4[i] = g1[i];
            }
            #pragma unroll
            for (int it = 0; it < 3; ++it) {
                int i = it * 256 + tid;
                if (i < 625) s4[625 + i] = g2[i];
            }
            if (tid < 100) s[5000 + tid] = vb1[(size_t)nv * 100 + tid];
            if (tid < 25)  s[5100 + tid] = vb2[(size_t)nv * 25 + tid];
        }
        __syncthreads();

        __bf16* dst = wvar + (size_t)nv * VAR_W_ELEMS;

        // L1 frags: 7 frags x 64 lanes x bf16x8
        #pragma unroll
        for (int it = 0; it < 2; ++it) {
            int i = it * 256 + tid;
            if (i < 448) {
                int l = i & 63, mt = i >> 6;
                int q = l >> 4, c = l & 15, h = mt * 16 + c;
                int hc = min(h, 99);
                bf16x8 v;
                #pragma unroll
                for (int j = 0; j < 8; ++j) {
                    int k  = q * 8 + j;
                    int kc = min(k, 24);
                    float wv = s[kc * 100 + hc];
                    float x = 0.0f;
                    if (h < 100) x = (k < 25) ? wv : ((k == 25) ? s[5000 + h] : 0.0f);
                    v[j] = (__bf16)x;
                }
                *(bf16x8*)(dst + i * 8) = v;
            }
        }
        // L2 frags: 14 frags x 64 lanes x bf16x4
        #pragma unroll
        for (int it = 0; it < 4; ++it) {
            int i = it * 256 + tid;
            if (i < 896) {
                int l = i & 63, f = i >> 6;
                int ks = f >> 1, mt = f & 1;
                int q = l >> 4, c = l & 15, o = mt * 16 + c;
                int oc = min(o, 24);
                bf16x4 v;
                #pragma unroll
                for (int r = 0; r < 4; ++r) {
                    int k  = ks * 16 + q * 4 + r;
                    int kc = min(k, 99);
                    float wv = s[2500 + kc * 25 + oc];
                    float x = 0.0f;
                    if (o < 25) x = (k < 100) ? wv : ((k == 100) ? s[5100 + o] : 0.0f);
                    v[r] = (__bf16)x;
                }
                *(bf16x4*)(dst + VAR_L2_OFF + i * 4) = v;
            }
        }
    } else if (bid < 3584) {
        // ---------------- syndrome sign transpose ----------------
        int idx = (bid - 3072) * 256 + tid;        // m*128 + b
        int m = idx >> 7, b = idx & 127;
        sgnT[idx] = (float)(1 - 2 * synd[(size_t)b * MM + m]);
    } else {
        // ---------------- v2c init ----------------
        int idx = (bid - 3584) * 256 + tid;
        int e = idx >> 7;
        bf16x8 v;
        #pragma unroll
        for (int j = 0; j < 8; ++j) v[j] = (__bf16)0.0f;
        v[0] = (__bf16)prior[e / 3];
        *(bf16x8*)(v2c + (size_t)idx * 8) = v;
    }
}

// ---------------------------------------------------------------------------
// Check MLP, transposed register-chained compute + LDS-tile epilogue
// with 16B-chunk coalesced stores.
// ---------------------------------------------------------------------------
#define CPITCH 58   // Y tile pitch (elements); 29c mod 32 spreads banks
__global__ __launch_bounds__(256, 3)
void chk_kernel(const __bf16* __restrict__ wchk,
                const float* __restrict__ sgnT,
                const int* __restrict__ v2c_gather,
                const __bf16* __restrict__ v2c, __bf16* __restrict__ c2v)
{
    const int m = blockIdx.x;
    const int tid = threadIdx.x;
    const int w = tid >> 6, l = tid & 63, q = l >> 4, c = l & 15;

    __shared__ __align__(16) __bf16 wlds[CHK_W_ELEMS];      // 43.5 KB
    __shared__ __align__(16) __bf16 ytile[4 * 16 * CPITCH]; // 7.25 KB
    {
        const __bf16* src = wchk + (size_t)m * CHK_W_ELEMS;
        for (int i = tid; i < CHK_W_ELEMS / 8; i += 256)
            *(u32x4*)(wlds + i * 8) = *(const u32x4*)(src + i * 8);
    }
    const int e0 = v2c_gather[m * 6 + q];
    const int e1 = (q < 2) ? v2c_gather[m * 6 + 4 + q] : 0;
    __syncthreads();

    __bf16* myy = ytile + w * 16 * CPITCH;   // [batch 16][out 48], wave-private

    for (int t2 = 0; t2 < 2; ++t2) {
        const int bt = t2 * 64 + w * 16;

        // X^T B-frags
        bf16x8 b0 = *(const bf16x8*)(v2c + ((size_t)e0 * BB + bt + c) * 8);
        bf16x8 b1f;
        #pragma unroll
        for (int j = 0; j < 8; ++j) b1f[j] = (__bf16)0.0f;
        if (q < 2)       b1f = *(const bf16x8*)(v2c + ((size_t)e1 * BB + bt + c) * 8);
        else if (q == 2) b1f[0] = (__bf16)1.0f;   // bias row k=48

        // layer 1: 12 hidden tiles (x32)
        f32x4 acc[12];
        #pragma unroll
        for (int mt = 0; mt < 12; ++mt) {
            bf16x8 a0 = *(const bf16x8*)(wlds + (mt * 2 + 0) * 512 + l * 8);
            bf16x8 a1 = *(const bf16x8*)(wlds + (mt * 2 + 1) * 512 + l * 8);
            f32x4 z = {0.f, 0.f, 0.f, 0.f};
            z = __builtin_amdgcn_mfma_f32_16x16x32_bf16(a0, b0, z, 0, 0, 0);
            z = __builtin_amdgcn_mfma_f32_16x16x32_bf16(a1, b1f, z, 0, 0, 0);
            acc[mt] = z;
        }

        // layer 2: 13 x16 k-steps, B-frag = gelu(acc) straight from registers
        f32x4 acc2[3];
        #pragma unroll
        for (int mt = 0; mt < 3; ++mt) acc2[mt] = (f32x4){0.f, 0.f, 0.f, 0.f};
        #pragma unroll
        for (int ks = 0; ks < 13; ++ks) {
            bf16x4 bf;
            if (ks < 12) {
                #pragma unroll
                for (int r = 0; r < 4; ++r) bf[r] = (__bf16)gelu_fast(acc[ks][r]);
            } else {
                #pragma unroll
                for (int r = 0; r < 4; ++r) bf[r] = (__bf16)0.0f;
                if (q == 0) bf[0] = (__bf16)1.0f;   // k=192 bias row
            }
            #pragma unroll
            for (int mt = 0; mt < 3; ++mt) {
                bf16x4 af = *(const bf16x4*)(wlds + CHK_L2_OFF + (ks * 3 + mt) * 256 + l * 4);
                acc2[mt] = mfma16(af, bf, acc2[mt]);
            }
        }

        // epilogue: sign + transpose via wave-private LDS tile [b][o]
        const float sg = sgnT[m * BB + bt + c];
        #pragma unroll
        for (int mt = 0; mt < 3; ++mt)
            #pragma unroll
            for (int r = 0; r < 4; ++r)
                myy[c * CPITCH + mt * 16 + q * 4 + r] = (__bf16)(acc2[mt][r] * sg);
        wave_lds_fence();

        // coalesced 16B chunk stores: (slot s, row) -> c2v[e=m*6+s][bt+row][0..7]
        {
            int s = l >> 4, row = l & 15;
            u32x4 vv = *(const u32x4*)(myy + row * CPITCH + s * 8);
            *(u32x4*)(c2v + ((size_t)(m * 6 + s) * BB + bt + row) * 8) = vv;
            if (l < 32) {
                int s2 = 4 + (l >> 4), row2 = l & 15;
                u32x4 v2 = *(const u32x4*)(myy + row2 * CPITCH + s2 * 8);
                *(u32x4*)(c2v + ((size_t)(m * 6 + s2) * BB + bt + row2) * 8) = v2;
            }
        }
        wave_lds_fence();   // reads done before next-t2 tile writes
    }
}

// ---------------------------------------------------------------------------
// Variable MLP, same structure. LLR (out=24) stored f32 from register.
// ---------------------------------------------------------------------------
#define VPITCH 26
__global__ __launch_bounds__(256, 4)
void var_kernel(const __bf16* __restrict__ wvar,
                const int* __restrict__ c2v_gather, const float* __restrict__ prior,
                const __bf16* __restrict__ c2v, __bf16* __restrict__ v2c,
                float* __restrict__ llr_out, int last)
{
    const int nv = blockIdx.x;
    const int tid = threadIdx.x;
    const int w = tid >> 6, l = tid & 63, q = l >> 4, c = l & 15;

    __shared__ __align__(16) __bf16 wlds[VAR_W_ELEMS];      // 14.3 KB
    __shared__ __align__(16) __bf16 ytile[4 * 16 * VPITCH]; // 3.25 KB
    {
        const __bf16* src = wvar + (size_t)nv * VAR_W_ELEMS;
        for (int i = tid; i < VAR_W_ELEMS / 8; i += 256)
            *(u32x4*)(wlds + i * 8) = *(const u32x4*)(src + i * 8);
    }
    const int ep = (q < 3) ? c2v_gather[nv * 3 + q] : 0;
    const __bf16 prbf = (__bf16)prior[nv];
    __syncthreads();

    __bf16* myy = ytile + w * 16 * VPITCH;   // [batch 16][out 24]

    for (int t2 = 0; t2 < 2; ++t2) {
        const int bt = t2 * 64 + w * 16;

        bf16x8 b0;
        #pragma unroll
        for (int j = 0; j < 8; ++j) b0[j] = (__bf16)0.0f;
        if (q < 3) b0 = *(const bf16x8*)(c2v + ((size_t)ep * BB + bt + c) * 8);
        else { b0[0] = prbf; b0[1] = (__bf16)1.0f; }   // k=24 prior, k=25 bias

        f32x4 acc[7];
        #pragma unroll
        for (int mt = 0; mt < 7; ++mt) {
            bf16x8 a0 = *(const bf16x8*)(wlds + mt * 512 + l * 8);
            f32x4 z = {0.f, 0.f, 0.f, 0.f};
            acc[mt] = __builtin_amdgcn_mfma_f32_16x16x32_bf16(a0, b0, z, 0, 0, 0);
        }

        f32x4 acc2[2];
        acc2[0] = (f32x4){0.f, 0.f, 0.f, 0.f};
        acc2[1] = (f32x4){0.f, 0.f, 0.f, 0.f};
        #pragma unroll
        for (int ks = 0; ks < 7; ++ks) {
            bf16x4 bf;
            #pragma unroll
            for (int r = 0; r < 4; ++r) bf[r] = (__bf16)gelu_fast(acc[ks][r]);
            if (ks == 6 && q == 1) bf[0] = (__bf16)1.0f;   // k=100 bias row
            #pragma unroll
            for (int mt = 0; mt < 2; ++mt) {
                bf16x4 af = *(const bf16x4*)(wlds + VAR_L2_OFF + (ks * 2 + mt) * 256 + l * 4);
                acc2[mt] = mfma16(af, bf, acc2[mt]);
            }
        }

        // epilogue: messages (o<24) via LDS tile; LLR (o=24) f32 direct
        #pragma unroll
        for (int r = 0; r < 4; ++r)
            myy[c * VPITCH + q * 4 + r] = (__bf16)acc2[0][r];
        if (q < 2)
            #pragma unroll
            for (int r = 0; r < 4; ++r)
                myy[c * VPITCH + 16 + q * 4 + r] = (__bf16)acc2[1][r];
        if (q == 2) llr_out[(size_t)(bt + c) * NN + nv] = acc2[1][0];
        wave_lds_fence();

        if (!last && l < 48) {
            int s = l >> 4, row = l & 15;
            u32x4 vv = *(const u32x4*)(myy + row * VPITCH + s * 8);
            *(u32x4*)(v2c + ((size_t)(nv * 3 + s) * BB + bt + row) * 8) = vv;
        }
        wave_lds_fence();
    }
}

extern "C" void kernel_launch(void* const* d_in, const int* in_sizes, int n_in,
                              void* d_out, int out_size, void* d_ws, size_t ws_size,
                              hipStream_t stream) {
    const int*   syndromes = (const int*)  d_in[0];
    const float* prior_llr = (const float*)d_in[1];
    const float* chk_w1    = (const float*)d_in[2];
    const float* chk_b1    = (const float*)d_in[3];
    const float* chk_w2    = (const float*)d_in[4];
    const float* chk_b2    = (const float*)d_in[5];
    const float* var_w1    = (const float*)d_in[6];
    const float* var_b1    = (const float*)d_in[7];
    const float* var_w2    = (const float*)d_in[8];
    const float* var_b2    = (const float*)d_in[9];
    const int*   c2v_g     = (const int*)  d_in[11];
    const int*   v2c_g     = (const int*)  d_in[12];

    float* out = (float*)d_out;

    __bf16* v2c  = (__bf16*)d_ws;                           // 12.6 MB
    __bf16* c2v  = v2c + (size_t)EE * BB * 8;               // 12.6 MB
    __bf16* wchk = c2v + (size_t)EE * BB * 8;               // 45.6 MB
    __bf16* wvar = wchk + (size_t)MM * CHK_W_ELEMS;         // 29.4 MB
    float*  sgnT = (float*)(wvar + (size_t)NN * VAR_W_ELEMS); // 512 KB

    prep_fused<<<PREP_GRID, 256, 0, stream>>>(chk_w1, chk_b1, chk_w2, chk_b2,
                                              var_w1, var_b1, var_w2, var_b2,
                                              syndromes, prior_llr,
                                              wchk, wvar, sgnT, v2c);

    for (int t = 0; t < TT; ++t) {
        chk_kernel<<<MM, 256, 0, stream>>>(wchk, sgnT, v2c_g, v2c, c2v);
        var_kernel<<<NN, 256, 0, stream>>>(wvar, c2v_g, prior_llr, c2v, v2c,
                                           out + (size_t)t * BB * NN,
                                           (t == TT - 1) ? 1 : 0);
    }
}

// Round 2
// 403.506 us; speedup vs baseline: 1.0507x; 1.0507x over previous
//
#include <hip/hip_runtime.h>
#include <math.h>

#define MM 1024      // checks
#define NN 2048      // vars
#define BB 128       // batch
#define TT 5         // iterations
#define EE 6144      // edges

typedef __bf16 bf16x8 __attribute__((ext_vector_type(8)));
typedef __bf16 bf16x4 __attribute__((ext_vector_type(4)));
typedef short  s16x4  __attribute__((ext_vector_type(4)));
typedef float  f32x4  __attribute__((ext_vector_type(4)));
typedef unsigned int u32x4 __attribute__((ext_vector_type(4)));

// prepped weight sizes (bf16 elements)
#define CHK_W_ELEMS 22272   // 24 x32-frags (512) + 39 x16-frags (256)
#define CHK_L2_OFF  12288
#define VAR_W_ELEMS 7168    // 7 x32-frags + 14 x16-frags
#define VAR_L2_OFF  3584

// Abramowitz-Stegun 7.1.26 erf (|eps| < 1.5e-7)
__device__ __forceinline__ float gelu_fast(float x) {
    float xe = x * 0.70710678118654752f;
    float ax = fabsf(xe);
    float t  = __builtin_amdgcn_rcpf(1.0f + 0.3275911f * ax);
    float p  = t * (0.254829592f + t * (-0.284496736f + t * (1.421413741f +
               t * (-1.453152027f + t * 1.061405429f))));
    float er = 1.0f - p * __expf(-xe * xe);
    er = copysignf(er, xe);
    return 0.5f * x * (1.0f + er);
}

// 16x16x16 bf16 MFMA: B-operand layout == C/D layout of a prior MFMA ->
// register-chained layer2 (no LDS transpose on the critical path).
__device__ __forceinline__ f32x4 mfma16(bf16x4 a, bf16x4 b, f32x4 c) {
#if __has_builtin(__builtin_amdgcn_mfma_f32_16x16x16bf16_1k)
    return __builtin_amdgcn_mfma_f32_16x16x16bf16_1k(
        __builtin_bit_cast(s16x4, a), __builtin_bit_cast(s16x4, b), c, 0, 0, 0);
#else
    f32x4 d;
    asm volatile("v_mfma_f32_16x16x16_bf16 %0, %1, %2, %3\n\ts_nop 4"
                 : "=v"(d) : "v"(a), "v"(b), "v"(c));
    return d;
#endif
}

// wave-private LDS fence (DS ops in-order per wave)
__device__ __forceinline__ void wave_lds_fence() {
    asm volatile("s_waitcnt lgkmcnt(0)" ::: "memory");
}

// ---------------------------------------------------------------------------
// prep_fused: (a) chk weight pack, (b) var weight pack, (c) sgnT, (d) v2c init.
//
// r1 lesson: 74.7 KB LDS -> 2 blocks/CU -> 20% occupancy -> 2.0 TB/s.
// r2: phase the packs so LDS stays at 24 KB (6 blocks/CU by LDS), and bound
// VGPR via __launch_bounds__(256,6). Each phase: coalesced float4 stage ->
// sync -> emission with LINEAR (perfectly coalesced) 16B/8B stores -> sync.
// Phases A1/B1 need no clamps at all; selects elsewhere read in-bounds LDS
// garbage then select 0 (safe: array is 6144 floats, max addr 6143).
// Block types by blockIdx.x:
//   [0,1024)      chk pack, one m per block
//   [1024,3072)   var pack, one nv per block
//   [3072,3584)   sgnT
//   [3584,6656)   v2c init
// ---------------------------------------------------------------------------
#define PREP_GRID (1024 + 2048 + 512 + 3072)

__global__ __launch_bounds__(256, 6)
void prep_fused(const float* __restrict__ cw1, const float* __restrict__ cb1,
                const float* __restrict__ cw2, const float* __restrict__ cb2,
                const float* __restrict__ vw1, const float* __restrict__ vb1,
                const float* __restrict__ vw2, const float* __restrict__ vb2,
                const int* __restrict__ synd, const float* __restrict__ prior,
                __bf16* __restrict__ wchk, __bf16* __restrict__ wvar,
                float* __restrict__ sgnT, __bf16* __restrict__ v2c)
{
    const int bid = blockIdx.x;
    const int tid = threadIdx.x;
    const int w = tid >> 6, l = tid & 63, q = l >> 4, c = l & 15;

    __shared__ __align__(16) float s[6144];   // 24 KB
    float4* s4 = (float4*)s;

    if (bid < 1024) {
        // ---------------- chk weight pack, 4 phases ----------------
        const int m = bid;
        const float4* g1 = (const float4*)(cw1 + (size_t)m * 9216);
        const float4* g2 = (const float4*)(cw2 + (size_t)m * 9216);
        __bf16* dst = wchk + (size_t)m * CHK_W_ELEMS;

        // ---- phase A1: w1 rows 0..31 (kt=0 frags), no selects ----
        #pragma unroll
        for (int it = 0; it < 6; ++it) s4[it * 256 + tid] = g1[it * 256 + tid];
        __syncthreads();
        #pragma unroll
        for (int it = 0; it < 3; ++it) {
            int mt = it * 4 + w;                  // 0..11
            int h = mt * 16 + c;
            bf16x8 v;
            #pragma unroll
            for (int j = 0; j < 8; ++j) v[j] = (__bf16)s[(q * 8 + j) * 192 + h];
            *(bf16x8*)(dst + (mt * 2) * 512 + l * 8) = v;
        }
        __syncthreads();

        // ---- phase A2: w1 rows 32..47 + b1 (kt=1 frags) ----
        #pragma unroll
        for (int it = 0; it < 3; ++it) s4[it * 256 + tid] = g1[1536 + it * 256 + tid];
        if (tid < 192) s[3072 + tid] = cb1[(size_t)m * 192 + tid];  // "row 16"
        __syncthreads();
        #pragma unroll
        for (int it = 0; it < 3; ++it) {
            int mt = it * 4 + w;
            int h = mt * 16 + c;
            bf16x8 v;
            #pragma unroll
            for (int j = 0; j < 8; ++j) {
                int lr = q * 8 + j;               // k = 32 + lr
                float wv = s[lr * 192 + h];       // lr<=16 valid (16 == bias row)
                v[j] = (__bf16)((lr <= 16) ? wv : 0.0f);
            }
            *(bf16x8*)(dst + (mt * 2 + 1) * 512 + l * 8) = v;
        }
        __syncthreads();

        // ---- phase B1: w2 rows 0..95 (ks=0..5), no selects ----
        #pragma unroll
        for (int it = 0; it < 5; ++it) {
            int i = it * 256 + tid;
            if (i < 1152) s4[i] = g2[i];
        }
        __syncthreads();
        #pragma unroll
        for (int it = 0; it < 5; ++it) {
            int fl = it * 4 + w;                  // 0..19
            if (fl < 18) {
                int ks = fl / 3, mt = fl % 3;
                int o = mt * 16 + c;
                bf16x4 v;
                #pragma unroll
                for (int r = 0; r < 4; ++r)
                    v[r] = (__bf16)s[(ks * 16 + q * 4 + r) * 48 + o];
                *(bf16x4*)(dst + CHK_L2_OFF + fl * 256 + l * 4) = v;
            }
        }
        __syncthreads();

        // ---- phase B2: w2 rows 96..191 + b2 (ks=6..12) ----
        #pragma unroll
        for (int it = 0; it < 5; ++it) {
            int i = it * 256 + tid;
            if (i < 1152) s4[i] = g2[1152 + i];
        }
        if (tid < 48) s[4608 + tid] = cb2[(size_t)m * 48 + tid];    // "row 96"
        __syncthreads();
        #pragma unroll
        for (int it = 0; it < 6; ++it) {
            int fl = it * 4 + w;                  // 0..23
            if (fl < 21) {
                int ks6 = fl / 3, mt = fl % 3;
                int o = mt * 16 + c;
                bf16x4 v;
                #pragma unroll
                for (int r = 0; r < 4; ++r) {
                    int lr = ks6 * 16 + q * 4 + r;       // k = 96 + lr
                    float wv = s[lr * 48 + o];           // lr<=96 valid (96 == bias)
                    v[r] = (__bf16)((lr <= 96) ? wv : 0.0f);
                }
                *(bf16x4*)(dst + CHK_L2_OFF + (18 + fl) * 256 + l * 4) = v;
            }
        }
    } else if (bid < 3072) {
        // ---------------- var weight pack, single phase (20.5 KB) ----------------
        const int nv = bid - 1024;
        const float4* g1 = (const float4*)(vw1 + (size_t)nv * 2500);
        const float4* g2 = (const float4*)(vw2 + (size_t)nv * 2500);
        __bf16* dst = wvar + (size_t)nv * VAR_W_ELEMS;

        #pragma unroll
        for (int it = 0; it < 3; ++it) {
            int i = it * 256 + tid;
            if (i < 625) s4[i] = g1[i];
        }
        #pragma unroll
        for (int it = 0; it < 3; ++it) {
            int i = it * 256 + tid;
            if (i < 625) s4[625 + i] = g2[i];
        }
        if (tid < 100) s[5000 + tid] = vb1[(size_t)nv * 100 + tid];
        if (tid < 25)  s[5100 + tid] = vb2[(size_t)nv * 25 + tid];
        __syncthreads();

        // L1 frags: 7 x 64 chunks of bf16x8
        #pragma unroll
        for (int it = 0; it < 2; ++it) {
            int mt = it * 4 + w;                  // 0..7
            if (mt < 7) {
                int i = it * 256 + tid;
                int h = mt * 16 + c, hc = min(h, 99);
                bf16x8 v;
                #pragma unroll
                for (int j = 0; j < 8; ++j) {
                    int k = q * 8 + j, kc = min(k, 24);
                    float wv = s[kc * 100 + hc];
                    float x = 0.0f;
                    if (h < 100) x = (k < 25) ? wv : ((k == 25) ? s[5000 + h] : 0.0f);
                    v[j] = (__bf16)x;
                }
                *(bf16x8*)(dst + i * 8) = v;
            }
        }
        // L2 frags: 14 x 64 chunks of bf16x4
        #pragma unroll
        for (int it = 0; it < 4; ++it) {
            int fl = it * 4 + w;                  // 0..15
            if (fl < 14) {
                int i = it * 256 + tid;
                int ks = fl >> 1, mt = fl & 1;
                int o = mt * 16 + c, oc = min(o, 24);
                bf16x4 v;
                #pragma unroll
                for (int r = 0; r < 4; ++r) {
                    int k = ks * 16 + q * 4 + r, kc = min(k, 99);
                    float wv = s[2500 + kc * 25 + oc];
                    float x = 0.0f;
                    if (o < 25) x = (k < 100) ? wv : ((k == 100) ? s[5100 + o] : 0.0f);
                    v[r] = (__bf16)x;
                }
                *(bf16x4*)(dst + VAR_L2_OFF + i * 4) = v;
            }
        }
    } else if (bid < 3584) {
        // ---------------- syndrome sign transpose ----------------
        int idx = (bid - 3072) * 256 + tid;        // m*128 + b
        int m = idx >> 7, b = idx & 127;
        sgnT[idx] = (float)(1 - 2 * synd[(size_t)b * MM + m]);
    } else {
        // ---------------- v2c init ----------------
        int idx = (bid - 3584) * 256 + tid;
        int e = idx >> 7;
        bf16x8 v;
        #pragma unroll
        for (int j = 0; j < 8; ++j) v[j] = (__bf16)0.0f;
        v[0] = (__bf16)prior[e / 3];
        *(bf16x8*)(v2c + (size_t)idx * 8) = v;
    }
}

// ---------------------------------------------------------------------------
// Check MLP, transposed register-chained compute + LDS-tile epilogue
// with 16B-chunk coalesced stores.
// ---------------------------------------------------------------------------
#define CPITCH 58   // Y tile pitch (elements); 29c mod 32 spreads banks
__global__ __launch_bounds__(256, 3)
void chk_kernel(const __bf16* __restrict__ wchk,
                const float* __restrict__ sgnT,
                const int* __restrict__ v2c_gather,
                const __bf16* __restrict__ v2c, __bf16* __restrict__ c2v)
{
    const int m = blockIdx.x;
    const int tid = threadIdx.x;
    const int w = tid >> 6, l = tid & 63, q = l >> 4, c = l & 15;

    __shared__ __align__(16) __bf16 wlds[CHK_W_ELEMS];      // 43.5 KB
    __shared__ __align__(16) __bf16 ytile[4 * 16 * CPITCH]; // 7.25 KB
    {
        const __bf16* src = wchk + (size_t)m * CHK_W_ELEMS;
        for (int i = tid; i < CHK_W_ELEMS / 8; i += 256)
            *(u32x4*)(wlds + i * 8) = *(const u32x4*)(src + i * 8);
    }
    const int e0 = v2c_gather[m * 6 + q];
    const int e1 = (q < 2) ? v2c_gather[m * 6 + 4 + q] : 0;
    __syncthreads();

    __bf16* myy = ytile + w * 16 * CPITCH;   // [batch 16][out 48], wave-private

    for (int t2 = 0; t2 < 2; ++t2) {
        const int bt = t2 * 64 + w * 16;

        // X^T B-frags
        bf16x8 b0 = *(const bf16x8*)(v2c + ((size_t)e0 * BB + bt + c) * 8);
        bf16x8 b1f;
        #pragma unroll
        for (int j = 0; j < 8; ++j) b1f[j] = (__bf16)0.0f;
        if (q < 2)       b1f = *(const bf16x8*)(v2c + ((size_t)e1 * BB + bt + c) * 8);
        else if (q == 2) b1f[0] = (__bf16)1.0f;   // bias row k=48

        // layer 1: 12 hidden tiles (x32)
        f32x4 acc[12];
        #pragma unroll
        for (int mt = 0; mt < 12; ++mt) {
            bf16x8 a0 = *(const bf16x8*)(wlds + (mt * 2 + 0) * 512 + l * 8);
            bf16x8 a1 = *(const bf16x8*)(wlds + (mt * 2 + 1) * 512 + l * 8);
            f32x4 z = {0.f, 0.f, 0.f, 0.f};
            z = __builtin_amdgcn_mfma_f32_16x16x32_bf16(a0, b0, z, 0, 0, 0);
            z = __builtin_amdgcn_mfma_f32_16x16x32_bf16(a1, b1f, z, 0, 0, 0);
            acc[mt] = z;
        }

        // layer 2: 13 x16 k-steps, B-frag = gelu(acc) straight from registers
        f32x4 acc2[3];
        #pragma unroll
        for (int mt = 0; mt < 3; ++mt) acc2[mt] = (f32x4){0.f, 0.f, 0.f, 0.f};
        #pragma unroll
        for (int ks = 0; ks < 13; ++ks) {
            bf16x4 bf;
            if (ks < 12) {
                #pragma unroll
                for (int r = 0; r < 4; ++r) bf[r] = (__bf16)gelu_fast(acc[ks][r]);
            } else {
                #pragma unroll
                for (int r = 0; r < 4; ++r) bf[r] = (__bf16)0.0f;
                if (q == 0) bf[0] = (__bf16)1.0f;   // k=192 bias row
            }
            #pragma unroll
            for (int mt = 0; mt < 3; ++mt) {
                bf16x4 af = *(const bf16x4*)(wlds + CHK_L2_OFF + (ks * 3 + mt) * 256 + l * 4);
                acc2[mt] = mfma16(af, bf, acc2[mt]);
            }
        }

        // epilogue: sign + transpose via wave-private LDS tile [b][o]
        const float sg = sgnT[m * BB + bt + c];
        #pragma unroll
        for (int mt = 0; mt < 3; ++mt)
            #pragma unroll
            for (int r = 0; r < 4; ++r)
                myy[c * CPITCH + mt * 16 + q * 4 + r] = (__bf16)(acc2[mt][r] * sg);
        wave_lds_fence();

        // coalesced 16B chunk stores: (slot s, row) -> c2v[e=m*6+s][bt+row][0..7]
        {
            int s = l >> 4, row = l & 15;
            u32x4 vv = *(const u32x4*)(myy + row * CPITCH + s * 8);
            *(u32x4*)(c2v + ((size_t)(m * 6 + s) * BB + bt + row) * 8) = vv;
            if (l < 32) {
                int s2 = 4 + (l >> 4), row2 = l & 15;
                u32x4 v2 = *(const u32x4*)(myy + row2 * CPITCH + s2 * 8);
                *(u32x4*)(c2v + ((size_t)(m * 6 + s2) * BB + bt + row2) * 8) = v2;
            }
        }
        wave_lds_fence();   // reads done before next-t2 tile writes
    }
}

// ---------------------------------------------------------------------------
// Variable MLP, same structure. LLR (out=24) stored f32 from register.
// ---------------------------------------------------------------------------
#define VPITCH 26
__global__ __launch_bounds__(256, 4)
void var_kernel(const __bf16* __restrict__ wvar,
                const int* __restrict__ c2v_gather, const float* __restrict__ prior,
                const __bf16* __restrict__ c2v, __bf16* __restrict__ v2c,
                float* __restrict__ llr_out, int last)
{
    const int nv = blockIdx.x;
    const int tid = threadIdx.x;
    const int w = tid >> 6, l = tid & 63, q = l >> 4, c = l & 15;

    __shared__ __align__(16) __bf16 wlds[VAR_W_ELEMS];      // 14.3 KB
    __shared__ __align__(16) __bf16 ytile[4 * 16 * VPITCH]; // 3.25 KB
    {
        const __bf16* src = wvar + (size_t)nv * VAR_W_ELEMS;
        for (int i = tid; i < VAR_W_ELEMS / 8; i += 256)
            *(u32x4*)(wlds + i * 8) = *(const u32x4*)(src + i * 8);
    }
    const int ep = (q < 3) ? c2v_gather[nv * 3 + q] : 0;
    const __bf16 prbf = (__bf16)prior[nv];
    __syncthreads();

    __bf16* myy = ytile + w * 16 * VPITCH;   // [batch 16][out 24]

    for (int t2 = 0; t2 < 2; ++t2) {
        const int bt = t2 * 64 + w * 16;

        bf16x8 b0;
        #pragma unroll
        for (int j = 0; j < 8; ++j) b0[j] = (__bf16)0.0f;
        if (q < 3) b0 = *(const bf16x8*)(c2v + ((size_t)ep * BB + bt + c) * 8);
        else { b0[0] = prbf; b0[1] = (__bf16)1.0f; }   // k=24 prior, k=25 bias

        f32x4 acc[7];
        #pragma unroll
        for (int mt = 0; mt < 7; ++mt) {
            bf16x8 a0 = *(const bf16x8*)(wlds + mt * 512 + l * 8);
            f32x4 z = {0.f, 0.f, 0.f, 0.f};
            acc[mt] = __builtin_amdgcn_mfma_f32_16x16x32_bf16(a0, b0, z, 0, 0, 0);
        }

        f32x4 acc2[2];
        acc2[0] = (f32x4){0.f, 0.f, 0.f, 0.f};
        acc2[1] = (f32x4){0.f, 0.f, 0.f, 0.f};
        #pragma unroll
        for (int ks = 0; ks < 7; ++ks) {
            bf16x4 bf;
            #pragma unroll
            for (int r = 0; r < 4; ++r) bf[r] = (__bf16)gelu_fast(acc[ks][r]);
            if (ks == 6 && q == 1) bf[0] = (__bf16)1.0f;   // k=100 bias row
            #pragma unroll
            for (int mt = 0; mt < 2; ++mt) {
                bf16x4 af = *(const bf16x4*)(wlds + VAR_L2_OFF + (ks * 2 + mt) * 256 + l * 4);
                acc2[mt] = mfma16(af, bf, acc2[mt]);
            }
        }

        // epilogue: messages (o<24) via LDS tile; LLR (o=24) f32 direct
        #pragma unroll
        for (int r = 0; r < 4; ++r)
            myy[c * VPITCH + q * 4 + r] = (__bf16)acc2[0][r];
        if (q < 2)
            #pragma unroll
            for (int r = 0; r < 4; ++r)
                myy[c * VPITCH + 16 + q * 4 + r] = (__bf16)acc2[1][r];
        if (q == 2) llr_out[(size_t)(bt + c) * NN + nv] = acc2[1][0];
        wave_lds_fence();

        if (!last && l < 48) {
            int s = l >> 4, row = l & 15;
            u32x4 vv = *(const u32x4*)(myy + row * VPITCH + s * 8);
            *(u32x4*)(v2c + ((size_t)(nv * 3 + s) * BB + bt + row) * 8) = vv;
        }
        wave_lds_fence();
    }
}

extern "C" void kernel_launch(void* const* d_in, const int* in_sizes, int n_in,
                              void* d_out, int out_size, void* d_ws, size_t ws_size,
                              hipStream_t stream) {
    const int*   syndromes = (const int*)  d_in[0];
    const float* prior_llr = (const float*)d_in[1];
    const float* chk_w1    = (const float*)d_in[2];
    const float* chk_b1    = (const float*)d_in[3];
    const float* chk_w2    = (const float*)d_in[4];
    const float* chk_b2    = (const float*)d_in[5];
    const float* var_w1    = (const float*)d_in[6];
    const float* var_b1    = (const float*)d_in[7];
    const float* var_w2    = (const float*)d_in[8];
    const float* var_b2    = (const float*)d_in[9];
    const int*   c2v_g     = (const int*)  d_in[11];
    const int*   v2c_g     = (const int*)  d_in[12];

    float* out = (float*)d_out;

    __bf16* v2c  = (__bf16*)d_ws;                           // 12.6 MB
    __bf16* c2v  = v2c + (size_t)EE * BB * 8;               // 12.6 MB
    __bf16* wchk = c2v + (size_t)EE * BB * 8;               // 45.6 MB
    __bf16* wvar = wchk + (size_t)MM * CHK_W_ELEMS;         // 29.4 MB
    float*  sgnT = (float*)(wvar + (size_t)NN * VAR_W_ELEMS); // 512 KB

    prep_fused<<<PREP_GRID, 256, 0, stream>>>(chk_w1, chk_b1, chk_w2, chk_b2,
                                              var_w1, var_b1, var_w2, var_b2,
                                              syndromes, prior_llr,
                                              wchk, wvar, sgnT, v2c);

    for (int t = 0; t < TT; ++t) {
        chk_kernel<<<MM, 256, 0, stream>>>(wchk, sgnT, v2c_g, v2c, c2v);
        var_kernel<<<NN, 256, 0, stream>>>(wvar, c2v_g, prior_llr, c2v, v2c,
                                           out + (size_t)t * BB * NN,
                                           (t == TT - 1) ? 1 : 0);
    }
}

// Round 3
// 399.336 us; speedup vs baseline: 1.0617x; 1.0104x over previous
//
#include <hip/hip_runtime.h>
#include <math.h>

#define MM 1024      // checks
#define NN 2048      // vars
#define BB 128       // batch
#define TT 5         // iterations
#define EE 6144      // edges

typedef __bf16 bf16x8 __attribute__((ext_vector_type(8)));
typedef __bf16 bf16x4 __attribute__((ext_vector_type(4)));
typedef short  s16x4  __attribute__((ext_vector_type(4)));
typedef float  f32x4  __attribute__((ext_vector_type(4)));
typedef unsigned int u32x4 __attribute__((ext_vector_type(4)));

// prepped weight sizes (bf16 elements)
#define CHK_W_ELEMS 22272   // 24 x32-frags (512) + 39 x16-frags (256)
#define CHK_L2_OFF  12288
#define VAR_W_ELEMS 7168    // 7 x32-frags + 14 x16-frags
#define VAR_L2_OFF  3584

// Abramowitz-Stegun 7.1.26 erf (|eps| < 1.5e-7)
__device__ __forceinline__ float gelu_fast(float x) {
    float xe = x * 0.70710678118654752f;
    float ax = fabsf(xe);
    float t  = __builtin_amdgcn_rcpf(1.0f + 0.3275911f * ax);
    float p  = t * (0.254829592f + t * (-0.284496736f + t * (1.421413741f +
               t * (-1.453152027f + t * 1.061405429f))));
    float er = 1.0f - p * __expf(-xe * xe);
    er = copysignf(er, xe);
    return 0.5f * x * (1.0f + er);
}

// 16x16x16 bf16 MFMA: B-operand layout == C/D layout of a prior MFMA ->
// register-chained layer2 (no LDS transpose on the critical path).
__device__ __forceinline__ f32x4 mfma16(bf16x4 a, bf16x4 b, f32x4 c) {
#if __has_builtin(__builtin_amdgcn_mfma_f32_16x16x16bf16_1k)
    return __builtin_amdgcn_mfma_f32_16x16x16bf16_1k(
        __builtin_bit_cast(s16x4, a), __builtin_bit_cast(s16x4, b), c, 0, 0, 0);
#else
    f32x4 d;
    asm volatile("v_mfma_f32_16x16x16_bf16 %0, %1, %2, %3\n\ts_nop 4"
                 : "=v"(d) : "v"(a), "v"(b), "v"(c));
    return d;
#endif
}

// wave-private LDS fence (DS ops in-order per wave)
__device__ __forceinline__ void wave_lds_fence() {
    asm volatile("s_waitcnt lgkmcnt(0)" ::: "memory");
}

// ---------------------------------------------------------------------------
// prep_fused r3: BARRIER-FREE wave-private packing.
// r2 lesson: phased stage->sync->emit at 50% occupancy still only 2.6 TB/s --
// barrier drain serializes read and write phases. r3: each wave owns a
// 1664-float LDS slice and runs its own independent task stream
// (coalesced f4 stage -> wave-local fence -> linear coalesced frag emit).
// No __syncthreads anywhere in the pack path; 6 blocks/CU x 4 decoupled
// waves keep global loads in flight continuously.
// Block types by blockIdx.x:
//   [0,1024)      chk pack, one m per block
//   [1024,3072)   var pack, one nv per block
//   [3072,3584)   sgnT
//   [3584,6656)   v2c init
// ---------------------------------------------------------------------------
#define PREP_GRID (1024 + 2048 + 512 + 3072)

__global__ __launch_bounds__(256, 6)
void prep_fused(const float* __restrict__ cw1, const float* __restrict__ cb1,
                const float* __restrict__ cw2, const float* __restrict__ cb2,
                const float* __restrict__ vw1, const float* __restrict__ vb1,
                const float* __restrict__ vw2, const float* __restrict__ vb2,
                const int* __restrict__ synd, const float* __restrict__ prior,
                __bf16* __restrict__ wchk, __bf16* __restrict__ wvar,
                float* __restrict__ sgnT, __bf16* __restrict__ v2c)
{
    const int bid = blockIdx.x;
    const int tid = threadIdx.x;
    const int w = tid >> 6, l = tid & 63, q = l >> 4, c = l & 15;

    __shared__ __align__(16) float s[6656];   // 26 KB = 4 x 1664-float wave slices
    float* sw = s + w * 1664;                  // wave-private slice

    if (bid < 1024) {
        // ================= chk weight pack (one m) =================
        const int m = bid;
        const float* w1p = cw1 + (size_t)m * 9216;
        const float* w2p = cw2 + (size_t)m * 9216;
        __bf16* dst = wchk + (size_t)m * CHK_W_ELEMS;

        // ---- w1, col slice [48w, 48w+48), kt=0 (rows 0..31); pitch 50 ----
        #pragma unroll
        for (int i0 = 0; i0 < 6; ++i0) {
            int i = i0 * 64 + l;
            int r = i / 12, c4 = i % 12;
            float4 v = *(const float4*)(w1p + r * 192 + w * 48 + c4 * 4);
            *(float2*)(sw + r * 50 + c4 * 4)     = make_float2(v.x, v.y);
            *(float2*)(sw + r * 50 + c4 * 4 + 2) = make_float2(v.z, v.w);
        }
        wave_lds_fence();
        #pragma unroll
        for (int d = 0; d < 3; ++d) {
            int mt = 3 * w + d;
            bf16x8 v;
            #pragma unroll
            for (int j = 0; j < 8; ++j)
                v[j] = (__bf16)sw[(q * 8 + j) * 50 + d * 16 + c];
            *(bf16x8*)(dst + (mt * 2) * 512 + l * 8) = v;
        }
        wave_lds_fence();

        // ---- w1 kt=1 (rows 32..47 local 0..15, bias row 16) ----
        #pragma unroll
        for (int i0 = 0; i0 < 4; ++i0) {
            int i = i0 * 64 + l;
            if (i < 204) {
                int r = i / 12, c4 = i % 12;
                const float* src = (r < 16)
                    ? (w1p + (32 + r) * 192 + w * 48 + c4 * 4)
                    : (cb1 + (size_t)m * 192 + w * 48 + c4 * 4);
                float4 v = *(const float4*)src;
                *(float2*)(sw + r * 50 + c4 * 4)     = make_float2(v.x, v.y);
                *(float2*)(sw + r * 50 + c4 * 4 + 2) = make_float2(v.z, v.w);
            }
        }
        wave_lds_fence();
        #pragma unroll
        for (int d = 0; d < 3; ++d) {
            int mt = 3 * w + d;
            bf16x8 v;
            #pragma unroll
            for (int j = 0; j < 8; ++j) {
                int lr = q * 8 + j;                  // k = 32 + lr
                float wv = sw[lr * 50 + d * 16 + c]; // in-bounds garbage ok
                v[j] = (__bf16)((lr <= 16) ? wv : 0.0f);
            }
            *(bf16x8*)(dst + (mt * 2 + 1) * 512 + l * 8) = v;
        }
        wave_lds_fence();

        // ---- w2 tasks: t in 0..8 = (kb,mt) tiles; t=9 = ks12 bias frags ----
        for (int t = w; t < 10; t += 4) {
            if (t < 9) {
                const int kb = t / 3, mt = t - kb * 3;
                // stage rows [64kb, 64kb+64), cols [16mt, 16mt+16); pitch 20
                #pragma unroll
                for (int i0 = 0; i0 < 4; ++i0) {
                    int i = i0 * 64 + l;
                    int r = i >> 2, c4 = i & 3;
                    float4 v = *(const float4*)(w2p + (kb * 64 + r) * 48 + mt * 16 + c4 * 4);
                    *(float4*)(sw + r * 20 + c4 * 4) = v;
                }
                wave_lds_fence();
                #pragma unroll
                for (int kk = 0; kk < 4; ++kk) {
                    bf16x4 v;
                    #pragma unroll
                    for (int r = 0; r < 4; ++r)
                        v[r] = (__bf16)sw[(kk * 16 + q * 4 + r) * 20 + c];
                    *(bf16x4*)(dst + CHK_L2_OFF + ((kb * 4 + kk) * 3 + mt) * 256 + l * 4) = v;
                }
                wave_lds_fence();
            } else {
                // ks = 12: only k==192 (q==0, r==0) is the bias row
                #pragma unroll
                for (int mt = 0; mt < 3; ++mt) {
                    bf16x4 v;
                    #pragma unroll
                    for (int r = 0; r < 4; ++r) v[r] = (__bf16)0.0f;
                    if (q == 0) v[0] = (__bf16)cb2[(size_t)m * 48 + mt * 16 + c];
                    *(bf16x4*)(dst + CHK_L2_OFF + (36 + mt) * 256 + l * 4) = v;
                }
            }
        }
    } else if (bid < 3072) {
        // ================= var weight pack (one nv) =================
        const int nv = bid - 1024;
        const float* w1p = vw1 + (size_t)nv * 2500;
        const float* w2p = vw2 + (size_t)nv * 2500;
        __bf16* dst = wvar + (size_t)nv * VAR_W_ELEMS;

        // ---- w1: wave w<3 owns cols [32w,32w+32) (mt 2w,2w+1); w3 cols 96..99 (mt 6)
        //      rows 0..24 = weights, row 25 = bias; pitch 34
        if (w < 3) {
            #pragma unroll
            for (int i0 = 0; i0 < 4; ++i0) {
                int i = i0 * 64 + l;
                if (i < 208) {
                    int r = i >> 3, c4 = i & 7;
                    const float* src = (r < 25)
                        ? (w1p + r * 100 + w * 32 + c4 * 4)
                        : (vb1 + (size_t)nv * 100 + w * 32 + c4 * 4);
                    float4 v = *(const float4*)src;
                    *(float2*)(sw + r * 34 + c4 * 4)     = make_float2(v.x, v.y);
                    *(float2*)(sw + r * 34 + c4 * 4 + 2) = make_float2(v.z, v.w);
                }
            }
        } else {
            if (l < 26) {
                int r = l;
                const float* src = (r < 25) ? (w1p + r * 100 + 96)
                                            : (vb1 + (size_t)nv * 100 + 96);
                float4 v = *(const float4*)src;
                *(float2*)(sw + r * 34)     = make_float2(v.x, v.y);
                *(float2*)(sw + r * 34 + 2) = make_float2(v.z, v.w);
            }
        }
        wave_lds_fence();
        {
            const int nmt = (w < 3) ? 2 : 1;
            #pragma unroll
            for (int d = 0; d < 2; ++d) {
                if (d < nmt) {
                    const int mt = (w < 3) ? (2 * w + d) : 6;
                    const int h = mt * 16 + c;
                    bf16x8 v;
                    #pragma unroll
                    for (int j = 0; j < 8; ++j) {
                        int k = q * 8 + j;
                        float wv = sw[k * 34 + d * 16 + c];   // in-bounds garbage ok
                        v[j] = (__bf16)((h < 100 && k <= 25) ? wv : 0.0f);
                    }
                    *(bf16x8*)(dst + mt * 512 + l * 8) = v;
                }
            }
        }
        wave_lds_fence();

        // ---- w2: wave w<3 stages rows [32w,32w+32) flat (pitch 25); emits ks 2w,2w+1.
        //      w3 stages rows 96..99 + bias as "row 4"; emits ks 6.
        if (w < 3) {
            #pragma unroll
            for (int i0 = 0; i0 < 4; ++i0) {
                int i = i0 * 64 + l;
                if (i < 200)
                    *(float4*)(sw + i * 4) = *(const float4*)(w2p + 800 * w + i * 4);
            }
        } else {
            if (l < 25) *(float4*)(sw + l * 4) = *(const float4*)(w2p + 2400 + l * 4);
            if (l < 25) sw[100 + l] = vb2[(size_t)nv * 25 + l];
        }
        wave_lds_fence();
        {
            const int nks = (w < 3) ? 2 : 1;
            #pragma unroll
            for (int kk = 0; kk < 2; ++kk) {
                if (kk < nks) {
                    const int ks = (w < 3) ? (2 * w + kk) : 6;
                    #pragma unroll
                    for (int mt = 0; mt < 2; ++mt) {
                        const int o = mt * 16 + c;
                        bf16x4 v;
                        #pragma unroll
                        for (int r = 0; r < 4; ++r) {
                            float x;
                            if (w < 3) {
                                int lk = kk * 16 + q * 4 + r;     // k=32w+lk <= 95 < 100
                                float wv = sw[lk * 25 + o];
                                x = (o < 25) ? wv : 0.0f;
                            } else {
                                int lk = q * 4 + r;               // k = 96+lk; lk==4 -> bias
                                float wv = sw[lk * 25 + o];
                                x = (o < 25 && lk <= 4) ? wv : 0.0f;
                            }
                            v[r] = (__bf16)x;
                        }
                        *(bf16x4*)(dst + VAR_L2_OFF + (ks * 2 + mt) * 256 + l * 4) = v;
                    }
                }
            }
        }
    } else if (bid < 3584) {
        // ---------------- syndrome sign transpose ----------------
        int idx = (bid - 3072) * 256 + tid;        // m*128 + b
        int m = idx >> 7, b = idx & 127;
        sgnT[idx] = (float)(1 - 2 * synd[(size_t)b * MM + m]);
    } else {
        // ---------------- v2c init ----------------
        int idx = (bid - 3584) * 256 + tid;
        int e = idx >> 7;
        bf16x8 v;
        #pragma unroll
        for (int j = 0; j < 8; ++j) v[j] = (__bf16)0.0f;
        v[0] = (__bf16)prior[e / 3];
        *(bf16x8*)(v2c + (size_t)idx * 8) = v;
    }
}

// ---------------------------------------------------------------------------
// Check MLP, transposed register-chained compute + LDS-tile epilogue
// with 16B-chunk coalesced stores.
// ---------------------------------------------------------------------------
#define CPITCH 58   // Y tile pitch (elements); 29c mod 32 spreads banks
__global__ __launch_bounds__(256, 3)
void chk_kernel(const __bf16* __restrict__ wchk,
                const float* __restrict__ sgnT,
                const int* __restrict__ v2c_gather,
                const __bf16* __restrict__ v2c, __bf16* __restrict__ c2v)
{
    const int m = blockIdx.x;
    const int tid = threadIdx.x;
    const int w = tid >> 6, l = tid & 63, q = l >> 4, c = l & 15;

    __shared__ __align__(16) __bf16 wlds[CHK_W_ELEMS];      // 43.5 KB
    __shared__ __align__(16) __bf16 ytile[4 * 16 * CPITCH]; // 7.25 KB
    {
        const __bf16* src = wchk + (size_t)m * CHK_W_ELEMS;
        for (int i = tid; i < CHK_W_ELEMS / 8; i += 256)
            *(u32x4*)(wlds + i * 8) = *(const u32x4*)(src + i * 8);
    }
    const int e0 = v2c_gather[m * 6 + q];
    const int e1 = (q < 2) ? v2c_gather[m * 6 + 4 + q] : 0;
    __syncthreads();

    __bf16* myy = ytile + w * 16 * CPITCH;   // [batch 16][out 48], wave-private

    for (int t2 = 0; t2 < 2; ++t2) {
        const int bt = t2 * 64 + w * 16;

        // X^T B-frags
        bf16x8 b0 = *(const bf16x8*)(v2c + ((size_t)e0 * BB + bt + c) * 8);
        bf16x8 b1f;
        #pragma unroll
        for (int j = 0; j < 8; ++j) b1f[j] = (__bf16)0.0f;
        if (q < 2)       b1f = *(const bf16x8*)(v2c + ((size_t)e1 * BB + bt + c) * 8);
        else if (q == 2) b1f[0] = (__bf16)1.0f;   // bias row k=48

        // layer 1: 12 hidden tiles (x32)
        f32x4 acc[12];
        #pragma unroll
        for (int mt = 0; mt < 12; ++mt) {
            bf16x8 a0 = *(const bf16x8*)(wlds + (mt * 2 + 0) * 512 + l * 8);
            bf16x8 a1 = *(const bf16x8*)(wlds + (mt * 2 + 1) * 512 + l * 8);
            f32x4 z = {0.f, 0.f, 0.f, 0.f};
            z = __builtin_amdgcn_mfma_f32_16x16x32_bf16(a0, b0, z, 0, 0, 0);
            z = __builtin_amdgcn_mfma_f32_16x16x32_bf16(a1, b1f, z, 0, 0, 0);
            acc[mt] = z;
        }

        // layer 2: 13 x16 k-steps, B-frag = gelu(acc) straight from registers
        f32x4 acc2[3];
        #pragma unroll
        for (int mt = 0; mt < 3; ++mt) acc2[mt] = (f32x4){0.f, 0.f, 0.f, 0.f};
        #pragma unroll
        for (int ks = 0; ks < 13; ++ks) {
            bf16x4 bf;
            if (ks < 12) {
                #pragma unroll
                for (int r = 0; r < 4; ++r) bf[r] = (__bf16)gelu_fast(acc[ks][r]);
            } else {
                #pragma unroll
                for (int r = 0; r < 4; ++r) bf[r] = (__bf16)0.0f;
                if (q == 0) bf[0] = (__bf16)1.0f;   // k=192 bias row
            }
            #pragma unroll
            for (int mt = 0; mt < 3; ++mt) {
                bf16x4 af = *(const bf16x4*)(wlds + CHK_L2_OFF + (ks * 3 + mt) * 256 + l * 4);
                acc2[mt] = mfma16(af, bf, acc2[mt]);
            }
        }

        // epilogue: sign + transpose via wave-private LDS tile [b][o]
        const float sg = sgnT[m * BB + bt + c];
        #pragma unroll
        for (int mt = 0; mt < 3; ++mt)
            #pragma unroll
            for (int r = 0; r < 4; ++r)
                myy[c * CPITCH + mt * 16 + q * 4 + r] = (__bf16)(acc2[mt][r] * sg);
        wave_lds_fence();

        // coalesced 16B chunk stores: (slot s, row) -> c2v[e=m*6+s][bt+row][0..7]
        {
            int s = l >> 4, row = l & 15;
            u32x4 vv = *(const u32x4*)(myy + row * CPITCH + s * 8);
            *(u32x4*)(c2v + ((size_t)(m * 6 + s) * BB + bt + row) * 8) = vv;
            if (l < 32) {
                int s2 = 4 + (l >> 4), row2 = l & 15;
                u32x4 v2 = *(const u32x4*)(myy + row2 * CPITCH + s2 * 8);
                *(u32x4*)(c2v + ((size_t)(m * 6 + s2) * BB + bt + row2) * 8) = v2;
            }
        }
        wave_lds_fence();   // reads done before next-t2 tile writes
    }
}

// ---------------------------------------------------------------------------
// Variable MLP, same structure. LLR (out=24) stored f32 from register.
// ---------------------------------------------------------------------------
#define VPITCH 26
__global__ __launch_bounds__(256, 4)
void var_kernel(const __bf16* __restrict__ wvar,
                const int* __restrict__ c2v_gather, const float* __restrict__ prior,
                const __bf16* __restrict__ c2v, __bf16* __restrict__ v2c,
                float* __restrict__ llr_out, int last)
{
    const int nv = blockIdx.x;
    const int tid = threadIdx.x;
    const int w = tid >> 6, l = tid & 63, q = l >> 4, c = l & 15;

    __shared__ __align__(16) __bf16 wlds[VAR_W_ELEMS];      // 14.3 KB
    __shared__ __align__(16) __bf16 ytile[4 * 16 * VPITCH]; // 3.25 KB
    {
        const __bf16* src = wvar + (size_t)nv * VAR_W_ELEMS;
        for (int i = tid; i < VAR_W_ELEMS / 8; i += 256)
            *(u32x4*)(wlds + i * 8) = *(const u32x4*)(src + i * 8);
    }
    const int ep = (q < 3) ? c2v_gather[nv * 3 + q] : 0;
    const __bf16 prbf = (__bf16)prior[nv];
    __syncthreads();

    __bf16* myy = ytile + w * 16 * VPITCH;   // [batch 16][out 24]

    for (int t2 = 0; t2 < 2; ++t2) {
        const int bt = t2 * 64 + w * 16;

        bf16x8 b0;
        #pragma unroll
        for (int j = 0; j < 8; ++j) b0[j] = (__bf16)0.0f;
        if (q < 3) b0 = *(const bf16x8*)(c2v + ((size_t)ep * BB + bt + c) * 8);
        else { b0[0] = prbf; b0[1] = (__bf16)1.0f; }   // k=24 prior, k=25 bias

        f32x4 acc[7];
        #pragma unroll
        for (int mt = 0; mt < 7; ++mt) {
            bf16x8 a0 = *(const bf16x8*)(wlds + mt * 512 + l * 8);
            f32x4 z = {0.f, 0.f, 0.f, 0.f};
            acc[mt] = __builtin_amdgcn_mfma_f32_16x16x32_bf16(a0, b0, z, 0, 0, 0);
        }

        f32x4 acc2[2];
        acc2[0] = (f32x4){0.f, 0.f, 0.f, 0.f};
        acc2[1] = (f32x4){0.f, 0.f, 0.f, 0.f};
        #pragma unroll
        for (int ks = 0; ks < 7; ++ks) {
            bf16x4 bf;
            #pragma unroll
            for (int r = 0; r < 4; ++r) bf[r] = (__bf16)gelu_fast(acc[ks][r]);
            if (ks == 6 && q == 1) bf[0] = (__bf16)1.0f;   // k=100 bias row
            #pragma unroll
            for (int mt = 0; mt < 2; ++mt) {
                bf16x4 af = *(const bf16x4*)(wlds + VAR_L2_OFF + (ks * 2 + mt) * 256 + l * 4);
                acc2[mt] = mfma16(af, bf, acc2[mt]);
            }
        }

        // epilogue: messages (o<24) via LDS tile; LLR (o=24) f32 direct
        #pragma unroll
        for (int r = 0; r < 4; ++r)
            myy[c * VPITCH + q * 4 + r] = (__bf16)acc2[0][r];
        if (q < 2)
            #pragma unroll
            for (int r = 0; r < 4; ++r)
                myy[c * VPITCH + 16 + q * 4 + r] = (__bf16)acc2[1][r];
        if (q == 2) llr_out[(size_t)(bt + c) * NN + nv] = acc2[1][0];
        wave_lds_fence();

        if (!last && l < 48) {
            int s = l >> 4, row = l & 15;
            u32x4 vv = *(const u32x4*)(myy + row * VPITCH + s * 8);
            *(u32x4*)(v2c + ((size_t)(nv * 3 + s) * BB + bt + row) * 8) = vv;
        }
        wave_lds_fence();
    }
}

extern "C" void kernel_launch(void* const* d_in, const int* in_sizes, int n_in,
                              void* d_out, int out_size, void* d_ws, size_t ws_size,
                              hipStream_t stream) {
    const int*   syndromes = (const int*)  d_in[0];
    const float* prior_llr = (const float*)d_in[1];
    const float* chk_w1    = (const float*)d_in[2];
    const float* chk_b1    = (const float*)d_in[3];
    const float* chk_w2    = (const float*)d_in[4];
    const float* chk_b2    = (const float*)d_in[5];
    const float* var_w1    = (const float*)d_in[6];
    const float* var_b1    = (const float*)d_in[7];
    const float* var_w2    = (const float*)d_in[8];
    const float* var_b2    = (const float*)d_in[9];
    const int*   c2v_g     = (const int*)  d_in[11];
    const int*   v2c_g     = (const int*)  d_in[12];

    float* out = (float*)d_out;

    __bf16* v2c  = (__bf16*)d_ws;                           // 12.6 MB
    __bf16* c2v  = v2c + (size_t)EE * BB * 8;               // 12.6 MB
    __bf16* wchk = c2v + (size_t)EE * BB * 8;               // 45.6 MB
    __bf16* wvar = wchk + (size_t)MM * CHK_W_ELEMS;         // 29.4 MB
    float*  sgnT = (float*)(wvar + (size_t)NN * VAR_W_ELEMS); // 512 KB

    prep_fused<<<PREP_GRID, 256, 0, stream>>>(chk_w1, chk_b1, chk_w2, chk_b2,
                                              var_w1, var_b1, var_w2, var_b2,
                                              syndromes, prior_llr,
                                              wchk, wvar, sgnT, v2c);

    for (int t = 0; t < TT; ++t) {
        chk_kernel<<<MM, 256, 0, stream>>>(wchk, sgnT, v2c_g, v2c, c2v);
        var_kernel<<<NN, 256, 0, stream>>>(wvar, c2v_g, prior_llr, c2v, v2c,
                                           out + (size_t)t * BB * NN,
                                           (t == TT - 1) ? 1 : 0);
    }
}

// Round 4
// 386.765 us; speedup vs baseline: 1.0962x; 1.0325x over previous
//
#include <hip/hip_runtime.h>
#include <math.h>

#define MM 1024      // checks
#define NN 2048      // vars
#define BB 128       // batch
#define TT 5         // iterations
#define EE 6144      // edges

typedef __bf16 bf16x8 __attribute__((ext_vector_type(8)));
typedef __bf16 bf16x4 __attribute__((ext_vector_type(4)));
typedef short  s16x4  __attribute__((ext_vector_type(4)));
typedef float  f32x4  __attribute__((ext_vector_type(4)));
typedef unsigned int u32x4 __attribute__((ext_vector_type(4)));

typedef const __attribute__((address_space(1))) void* gas_p;
typedef __attribute__((address_space(3))) void* las_p;

// prepped weight sizes (bf16 elements)
#define CHK_W_ELEMS 22272   // 24 x32-frags (512) + 39 x16-frags (256)
#define CHK_L2_OFF  12288
#define VAR_W_ELEMS 7168    // 7 x32-frags + 14 x16-frags
#define VAR_L2_OFF  3584

// Abramowitz-Stegun 7.1.26 erf (|eps| < 1.5e-7)
__device__ __forceinline__ float gelu_fast(float x) {
    float xe = x * 0.70710678118654752f;
    float ax = fabsf(xe);
    float t  = __builtin_amdgcn_rcpf(1.0f + 0.3275911f * ax);
    float p  = t * (0.254829592f + t * (-0.284496736f + t * (1.421413741f +
               t * (-1.453152027f + t * 1.061405429f))));
    float er = 1.0f - p * __expf(-xe * xe);
    er = copysignf(er, xe);
    return 0.5f * x * (1.0f + er);
}

// 16x16x16 bf16 MFMA: B-operand layout == C/D layout of a prior MFMA ->
// register-chained layer2 (no LDS transpose on the critical path).
__device__ __forceinline__ f32x4 mfma16(bf16x4 a, bf16x4 b, f32x4 c) {
#if __has_builtin(__builtin_amdgcn_mfma_f32_16x16x16bf16_1k)
    return __builtin_amdgcn_mfma_f32_16x16x16bf16_1k(
        __builtin_bit_cast(s16x4, a), __builtin_bit_cast(s16x4, b), c, 0, 0, 0);
#else
    f32x4 d;
    asm volatile("v_mfma_f32_16x16x16_bf16 %0, %1, %2, %3\n\ts_nop 4"
                 : "=v"(d) : "v"(a), "v"(b), "v"(c));
    return d;
#endif
}

// wave-private LDS fence (DS ops in-order per wave)
__device__ __forceinline__ void wave_lds_fence() {
    asm volatile("s_waitcnt lgkmcnt(0)" ::: "memory");
}

// ---------------------------------------------------------------------------
// prep_fused r3: barrier-free wave-private packing. Pinned at ~2.9 TB/s
// (mixed R/W ceiling) across 4 structurally different implementations --
// kept as-is; no further prep work.
// ---------------------------------------------------------------------------
#define PREP_GRID (1024 + 2048 + 512 + 3072)

__global__ __launch_bounds__(256, 6)
void prep_fused(const float* __restrict__ cw1, const float* __restrict__ cb1,
                const float* __restrict__ cw2, const float* __restrict__ cb2,
                const float* __restrict__ vw1, const float* __restrict__ vb1,
                const float* __restrict__ vw2, const float* __restrict__ vb2,
                const int* __restrict__ synd, const float* __restrict__ prior,
                __bf16* __restrict__ wchk, __bf16* __restrict__ wvar,
                float* __restrict__ sgnT, __bf16* __restrict__ v2c)
{
    const int bid = blockIdx.x;
    const int tid = threadIdx.x;
    const int w = tid >> 6, l = tid & 63, q = l >> 4, c = l & 15;

    __shared__ __align__(16) float s[6656];   // 26 KB = 4 x 1664-float wave slices
    float* sw = s + w * 1664;                  // wave-private slice

    if (bid < 1024) {
        // ================= chk weight pack (one m) =================
        const int m = bid;
        const float* w1p = cw1 + (size_t)m * 9216;
        const float* w2p = cw2 + (size_t)m * 9216;
        __bf16* dst = wchk + (size_t)m * CHK_W_ELEMS;

        // ---- w1, col slice [48w, 48w+48), kt=0 (rows 0..31); pitch 50 ----
        #pragma unroll
        for (int i0 = 0; i0 < 6; ++i0) {
            int i = i0 * 64 + l;
            int r = i / 12, c4 = i % 12;
            float4 v = *(const float4*)(w1p + r * 192 + w * 48 + c4 * 4);
            *(float2*)(sw + r * 50 + c4 * 4)     = make_float2(v.x, v.y);
            *(float2*)(sw + r * 50 + c4 * 4 + 2) = make_float2(v.z, v.w);
        }
        wave_lds_fence();
        #pragma unroll
        for (int d = 0; d < 3; ++d) {
            int mt = 3 * w + d;
            bf16x8 v;
            #pragma unroll
            for (int j = 0; j < 8; ++j)
                v[j] = (__bf16)sw[(q * 8 + j) * 50 + d * 16 + c];
            *(bf16x8*)(dst + (mt * 2) * 512 + l * 8) = v;
        }
        wave_lds_fence();

        // ---- w1 kt=1 (rows 32..47 local 0..15, bias row 16) ----
        #pragma unroll
        for (int i0 = 0; i0 < 4; ++i0) {
            int i = i0 * 64 + l;
            if (i < 204) {
                int r = i / 12, c4 = i % 12;
                const float* src = (r < 16)
                    ? (w1p + (32 + r) * 192 + w * 48 + c4 * 4)
                    : (cb1 + (size_t)m * 192 + w * 48 + c4 * 4);
                float4 v = *(const float4*)src;
                *(float2*)(sw + r * 50 + c4 * 4)     = make_float2(v.x, v.y);
                *(float2*)(sw + r * 50 + c4 * 4 + 2) = make_float2(v.z, v.w);
            }
        }
        wave_lds_fence();
        #pragma unroll
        for (int d = 0; d < 3; ++d) {
            int mt = 3 * w + d;
            bf16x8 v;
            #pragma unroll
            for (int j = 0; j < 8; ++j) {
                int lr = q * 8 + j;                  // k = 32 + lr
                float wv = sw[lr * 50 + d * 16 + c]; // in-bounds garbage ok
                v[j] = (__bf16)((lr <= 16) ? wv : 0.0f);
            }
            *(bf16x8*)(dst + (mt * 2 + 1) * 512 + l * 8) = v;
        }
        wave_lds_fence();

        // ---- w2 tasks: t in 0..8 = (kb,mt) tiles; t=9 = ks12 bias frags ----
        for (int t = w; t < 10; t += 4) {
            if (t < 9) {
                const int kb = t / 3, mt = t - kb * 3;
                // stage rows [64kb, 64kb+64), cols [16mt, 16mt+16); pitch 20
                #pragma unroll
                for (int i0 = 0; i0 < 4; ++i0) {
                    int i = i0 * 64 + l;
                    int r = i >> 2, c4 = i & 3;
                    float4 v = *(const float4*)(w2p + (kb * 64 + r) * 48 + mt * 16 + c4 * 4);
                    *(float4*)(sw + r * 20 + c4 * 4) = v;
                }
                wave_lds_fence();
                #pragma unroll
                for (int kk = 0; kk < 4; ++kk) {
                    bf16x4 v;
                    #pragma unroll
                    for (int r = 0; r < 4; ++r)
                        v[r] = (__bf16)sw[(kk * 16 + q * 4 + r) * 20 + c];
                    *(bf16x4*)(dst + CHK_L2_OFF + ((kb * 4 + kk) * 3 + mt) * 256 + l * 4) = v;
                }
                wave_lds_fence();
            } else {
                // ks = 12: only k==192 (q==0, r==0) is the bias row
                #pragma unroll
                for (int mt = 0; mt < 3; ++mt) {
                    bf16x4 v;
                    #pragma unroll
                    for (int r = 0; r < 4; ++r) v[r] = (__bf16)0.0f;
                    if (q == 0) v[0] = (__bf16)cb2[(size_t)m * 48 + mt * 16 + c];
                    *(bf16x4*)(dst + CHK_L2_OFF + (36 + mt) * 256 + l * 4) = v;
                }
            }
        }
    } else if (bid < 3072) {
        // ================= var weight pack (one nv) =================
        const int nv = bid - 1024;
        const float* w1p = vw1 + (size_t)nv * 2500;
        const float* w2p = vw2 + (size_t)nv * 2500;
        __bf16* dst = wvar + (size_t)nv * VAR_W_ELEMS;

        if (w < 3) {
            #pragma unroll
            for (int i0 = 0; i0 < 4; ++i0) {
                int i = i0 * 64 + l;
                if (i < 208) {
                    int r = i >> 3, c4 = i & 7;
                    const float* src = (r < 25)
                        ? (w1p + r * 100 + w * 32 + c4 * 4)
                        : (vb1 + (size_t)nv * 100 + w * 32 + c4 * 4);
                    float4 v = *(const float4*)src;
                    *(float2*)(sw + r * 34 + c4 * 4)     = make_float2(v.x, v.y);
                    *(float2*)(sw + r * 34 + c4 * 4 + 2) = make_float2(v.z, v.w);
                }
            }
        } else {
            if (l < 26) {
                int r = l;
                const float* src = (r < 25) ? (w1p + r * 100 + 96)
                                            : (vb1 + (size_t)nv * 100 + 96);
                float4 v = *(const float4*)src;
                *(float2*)(sw + r * 34)     = make_float2(v.x, v.y);
                *(float2*)(sw + r * 34 + 2) = make_float2(v.z, v.w);
            }
        }
        wave_lds_fence();
        {
            const int nmt = (w < 3) ? 2 : 1;
            #pragma unroll
            for (int d = 0; d < 2; ++d) {
                if (d < nmt) {
                    const int mt = (w < 3) ? (2 * w + d) : 6;
                    const int h = mt * 16 + c;
                    bf16x8 v;
                    #pragma unroll
                    for (int j = 0; j < 8; ++j) {
                        int k = q * 8 + j;
                        float wv = sw[k * 34 + d * 16 + c];   // in-bounds garbage ok
                        v[j] = (__bf16)((h < 100 && k <= 25) ? wv : 0.0f);
                    }
                    *(bf16x8*)(dst + mt * 512 + l * 8) = v;
                }
            }
        }
        wave_lds_fence();

        if (w < 3) {
            #pragma unroll
            for (int i0 = 0; i0 < 4; ++i0) {
                int i = i0 * 64 + l;
                if (i < 200)
                    *(float4*)(sw + i * 4) = *(const float4*)(w2p + 800 * w + i * 4);
            }
        } else {
            if (l < 25) *(float4*)(sw + l * 4) = *(const float4*)(w2p + 2400 + l * 4);
            if (l < 25) sw[100 + l] = vb2[(size_t)nv * 25 + l];
        }
        wave_lds_fence();
        {
            const int nks = (w < 3) ? 2 : 1;
            #pragma unroll
            for (int kk = 0; kk < 2; ++kk) {
                if (kk < nks) {
                    const int ks = (w < 3) ? (2 * w + kk) : 6;
                    #pragma unroll
                    for (int mt = 0; mt < 2; ++mt) {
                        const int o = mt * 16 + c;
                        bf16x4 v;
                        #pragma unroll
                        for (int r = 0; r < 4; ++r) {
                            float x;
                            if (w < 3) {
                                int lk = kk * 16 + q * 4 + r;     // k=32w+lk <= 95 < 100
                                float wv = sw[lk * 25 + o];
                                x = (o < 25) ? wv : 0.0f;
                            } else {
                                int lk = q * 4 + r;               // k = 96+lk; lk==4 -> bias
                                float wv = sw[lk * 25 + o];
                                x = (o < 25 && lk <= 4) ? wv : 0.0f;
                            }
                            v[r] = (__bf16)x;
                        }
                        *(bf16x4*)(dst + VAR_L2_OFF + (ks * 2 + mt) * 256 + l * 4) = v;
                    }
                }
            }
        }
    } else if (bid < 3584) {
        // ---------------- syndrome sign transpose ----------------
        int idx = (bid - 3072) * 256 + tid;        // m*128 + b
        int m = idx >> 7, b = idx & 127;
        sgnT[idx] = (float)(1 - 2 * synd[(size_t)b * MM + m]);
    } else {
        // ---------------- v2c init ----------------
        int idx = (bid - 3584) * 256 + tid;
        int e = idx >> 7;
        bf16x8 v;
        #pragma unroll
        for (int j = 0; j < 8; ++j) v[j] = (__bf16)0.0f;
        v[0] = (__bf16)prior[e / 3];
        *(bf16x8*)(v2c + (size_t)idx * 8) = v;
    }
}

// ---------------------------------------------------------------------------
// chk layer helpers (unchanged math)
// ---------------------------------------------------------------------------
__device__ __forceinline__ void chk_layer1(const __bf16* wlds, int l,
                                           bf16x8 b0, bf16x8 b1, f32x4* acc)
{
    #pragma unroll
    for (int mt = 0; mt < 12; ++mt) {
        bf16x8 a0 = *(const bf16x8*)(wlds + (mt * 2 + 0) * 512 + l * 8);
        bf16x8 a1 = *(const bf16x8*)(wlds + (mt * 2 + 1) * 512 + l * 8);
        f32x4 z = {0.f, 0.f, 0.f, 0.f};
        z = __builtin_amdgcn_mfma_f32_16x16x32_bf16(a0, b0, z, 0, 0, 0);
        z = __builtin_amdgcn_mfma_f32_16x16x32_bf16(a1, b1, z, 0, 0, 0);
        acc[mt] = z;
    }
}

__device__ __forceinline__ void chk_layer2(const __bf16* wlds, int l, int q,
                                           const f32x4* acc, f32x4* acc2)
{
    #pragma unroll
    for (int mt = 0; mt < 3; ++mt) acc2[mt] = (f32x4){0.f, 0.f, 0.f, 0.f};
    #pragma unroll
    for (int ks = 0; ks < 13; ++ks) {
        bf16x4 bf;
        if (ks < 12) {
            #pragma unroll
            for (int r = 0; r < 4; ++r) bf[r] = (__bf16)gelu_fast(acc[ks][r]);
        } else {
            #pragma unroll
            for (int r = 0; r < 4; ++r) bf[r] = (__bf16)0.0f;
            if (q == 0) bf[0] = (__bf16)1.0f;   // k=192 bias row
        }
        #pragma unroll
        for (int mt = 0; mt < 3; ++mt) {
            bf16x4 af = *(const bf16x4*)(wlds + CHK_L2_OFF + (ks * 3 + mt) * 256 + l * 4);
            acc2[mt] = mfma16(af, bf, acc2[mt]);
        }
    }
}

// ---------------------------------------------------------------------------
// Check MLP r4: global_load_lds two-phase staging.
//  - edge-id gathers issued FIRST (their value-wait covers only themselves)
//  - B-frags + signs for BOTH t2 halves prefetched into regs (overlaps stage)
//  - 11 gload_lds rounds; rounds 0-5 = layer-1 frags. vmcnt(5) -> barrier
//    releases layer1 while layer-2 weights still in flight; vmcnt(0) ->
//    barrier before any layer-2 read. (vmcnt retires in issue order, so
//    vmcnt(5) guarantees >=6 oldest stage rounds complete for any placement
//    of the extra prefetch loads.)
// ---------------------------------------------------------------------------
#define CPITCH 58   // Y tile pitch (elements); 29c mod 32 spreads banks
__global__ __launch_bounds__(256, 3)
void chk_kernel(const __bf16* __restrict__ wchk,
                const float* __restrict__ sgnT,
                const int* __restrict__ v2c_gather,
                const __bf16* __restrict__ v2c, __bf16* __restrict__ c2v)
{
    const int m = blockIdx.x;
    const int tid = threadIdx.x;
    const int w = tid >> 6, l = tid & 63, q = l >> 4, c = l & 15;

    __shared__ __align__(16) __bf16 wlds[CHK_W_ELEMS];      // 43.5 KB
    __shared__ __align__(16) __bf16 ytile[4 * 16 * CPITCH]; // 7.25 KB

    // edge ids first
    const int e0 = v2c_gather[m * 6 + q];
    const int e1 = (q < 2) ? v2c_gather[m * 6 + 4 + q] : 0;

    // prefetch B-frags + signs for both t2 halves
    bf16x8 bA[2], bB[2];
    float sg[2];
    #pragma unroll
    for (int t2 = 0; t2 < 2; ++t2) {
        const int bt = t2 * 64 + w * 16;
        bA[t2] = *(const bf16x8*)(v2c + ((size_t)e0 * BB + bt + c) * 8);
        bf16x8 bb;
        #pragma unroll
        for (int j = 0; j < 8; ++j) bb[j] = (__bf16)0.0f;
        if (q < 2)       bb = *(const bf16x8*)(v2c + ((size_t)e1 * BB + bt + c) * 8);
        else if (q == 2) bb[0] = (__bf16)1.0f;   // bias row k=48
        bB[t2] = bb;
        sg[t2] = sgnT[m * BB + bt + c];
    }

    // stage weights: 11 gload_lds rounds of 4KB (last partial: 224 chunks)
    {
        const __bf16* src = wchk + (size_t)m * CHK_W_ELEMS;
        #pragma unroll
        for (int r = 0; r < 10; ++r)
            __builtin_amdgcn_global_load_lds(
                (gas_p)(src + (r * 256 + tid) * 8),
                (las_p)(wlds + (r * 256 + tid) * 8), 16, 0, 0);
        if (tid < 224)
            __builtin_amdgcn_global_load_lds(
                (gas_p)(src + (2560 + tid) * 8),
                (las_p)(wlds + (2560 + tid) * 8), 16, 0, 0);
    }
    __builtin_amdgcn_sched_barrier(0);
    asm volatile("s_waitcnt vmcnt(5)" ::: "memory");   // L1 rounds 0-5 landed
    __syncthreads();

    __bf16* myy = ytile + w * 16 * CPITCH;   // [batch 16][out 48], wave-private

    // ---- t2=0 layer1 (only L1 region) while L2 weights stream in ----
    f32x4 acc[12];
    chk_layer1(wlds, l, bA[0], bB[0], acc);

    __builtin_amdgcn_sched_barrier(0);
    asm volatile("s_waitcnt vmcnt(0)" ::: "memory");   // L2 rounds landed
    __syncthreads();

    #pragma unroll
    for (int t2 = 0; t2 < 2; ++t2) {
        if (t2 == 1) chk_layer1(wlds, l, bA[1], bB[1], acc);
        const int bt = t2 * 64 + w * 16;

        f32x4 acc2[3];
        chk_layer2(wlds, l, q, acc, acc2);

        // epilogue: sign + transpose via wave-private LDS tile [b][o]
        #pragma unroll
        for (int mt = 0; mt < 3; ++mt)
            #pragma unroll
            for (int r = 0; r < 4; ++r)
                myy[c * CPITCH + mt * 16 + q * 4 + r] = (__bf16)(acc2[mt][r] * sg[t2]);
        wave_lds_fence();

        // coalesced 16B chunk stores: (slot s, row) -> c2v[e=m*6+s][bt+row][0..7]
        {
            int s = l >> 4, row = l & 15;
            u32x4 vv = *(const u32x4*)(myy + row * CPITCH + s * 8);
            *(u32x4*)(c2v + ((size_t)(m * 6 + s) * BB + bt + row) * 8) = vv;
            if (l < 32) {
                int s2 = 4 + (l >> 4), row2 = l & 15;
                u32x4 v2 = *(const u32x4*)(myy + row2 * CPITCH + s2 * 8);
                *(u32x4*)(c2v + ((size_t)(m * 6 + s2) * BB + bt + row2) * 8) = v2;
            }
        }
        wave_lds_fence();   // reads done before next-t2 tile writes
    }
}

// ---------------------------------------------------------------------------
// Variable MLP r4: gload_lds staging + b-frag prefetch + 5 blocks/CU.
// ---------------------------------------------------------------------------
#define VPITCH 26
__global__ __launch_bounds__(256, 5)
void var_kernel(const __bf16* __restrict__ wvar,
                const int* __restrict__ c2v_gather, const float* __restrict__ prior,
                const __bf16* __restrict__ c2v, __bf16* __restrict__ v2c,
                float* __restrict__ llr_out, int last)
{
    const int nv = blockIdx.x;
    const int tid = threadIdx.x;
    const int w = tid >> 6, l = tid & 63, q = l >> 4, c = l & 15;

    __shared__ __align__(16) __bf16 wlds[VAR_W_ELEMS];      // 14.3 KB
    __shared__ __align__(16) __bf16 ytile[4 * 16 * VPITCH]; // 3.25 KB

    const int ep = (q < 3) ? c2v_gather[nv * 3 + q] : 0;
    const __bf16 prbf = (__bf16)prior[nv];

    // prefetch both t2 B-frags
    bf16x8 bp[2];
    #pragma unroll
    for (int t2 = 0; t2 < 2; ++t2) {
        const int bt = t2 * 64 + w * 16;
        bf16x8 bb;
        #pragma unroll
        for (int j = 0; j < 8; ++j) bb[j] = (__bf16)0.0f;
        if (q < 3) bb = *(const bf16x8*)(c2v + ((size_t)ep * BB + bt + c) * 8);
        else { bb[0] = prbf; bb[1] = (__bf16)1.0f; }   // k=24 prior, k=25 bias
        bp[t2] = bb;
    }

    // stage weights: 3 full rounds + 1 partial (128 chunks)
    {
        const __bf16* src = wvar + (size_t)nv * VAR_W_ELEMS;
        #pragma unroll
        for (int r = 0; r < 3; ++r)
            __builtin_amdgcn_global_load_lds(
                (gas_p)(src + (r * 256 + tid) * 8),
                (las_p)(wlds + (r * 256 + tid) * 8), 16, 0, 0);
        if (tid < 128)
            __builtin_amdgcn_global_load_lds(
                (gas_p)(src + (768 + tid) * 8),
                (las_p)(wlds + (768 + tid) * 8), 16, 0, 0);
    }
    __builtin_amdgcn_sched_barrier(0);
    asm volatile("s_waitcnt vmcnt(0)" ::: "memory");
    __syncthreads();

    __bf16* myy = ytile + w * 16 * VPITCH;   // [batch 16][out 24]

    #pragma unroll
    for (int t2 = 0; t2 < 2; ++t2) {
        const int bt = t2 * 64 + w * 16;
        const bf16x8 b0 = bp[t2];

        f32x4 acc[7];
        #pragma unroll
        for (int mt = 0; mt < 7; ++mt) {
            bf16x8 a0 = *(const bf16x8*)(wlds + mt * 512 + l * 8);
            f32x4 z = {0.f, 0.f, 0.f, 0.f};
            acc[mt] = __builtin_amdgcn_mfma_f32_16x16x32_bf16(a0, b0, z, 0, 0, 0);
        }

        f32x4 acc2[2];
        acc2[0] = (f32x4){0.f, 0.f, 0.f, 0.f};
        acc2[1] = (f32x4){0.f, 0.f, 0.f, 0.f};
        #pragma unroll
        for (int ks = 0; ks < 7; ++ks) {
            bf16x4 bf;
            #pragma unroll
            for (int r = 0; r < 4; ++r) bf[r] = (__bf16)gelu_fast(acc[ks][r]);
            if (ks == 6 && q == 1) bf[0] = (__bf16)1.0f;   // k=100 bias row
            #pragma unroll
            for (int mt = 0; mt < 2; ++mt) {
                bf16x4 af = *(const bf16x4*)(wlds + VAR_L2_OFF + (ks * 2 + mt) * 256 + l * 4);
                acc2[mt] = mfma16(af, bf, acc2[mt]);
            }
        }

        // epilogue: messages (o<24) via LDS tile; LLR (o=24) f32 direct
        #pragma unroll
        for (int r = 0; r < 4; ++r)
            myy[c * VPITCH + q * 4 + r] = (__bf16)acc2[0][r];
        if (q < 2)
            #pragma unroll
            for (int r = 0; r < 4; ++r)
                myy[c * VPITCH + 16 + q * 4 + r] = (__bf16)acc2[1][r];
        if (q == 2) llr_out[(size_t)(bt + c) * NN + nv] = acc2[1][0];
        wave_lds_fence();

        if (!last && l < 48) {
            int s = l >> 4, row = l & 15;
            u32x4 vv = *(const u32x4*)(myy + row * VPITCH + s * 8);
            *(u32x4*)(v2c + ((size_t)(nv * 3 + s) * BB + bt + row) * 8) = vv;
        }
        wave_lds_fence();
    }
}

extern "C" void kernel_launch(void* const* d_in, const int* in_sizes, int n_in,
                              void* d_out, int out_size, void* d_ws, size_t ws_size,
                              hipStream_t stream) {
    const int*   syndromes = (const int*)  d_in[0];
    const float* prior_llr = (const float*)d_in[1];
    const float* chk_w1    = (const float*)d_in[2];
    const float* chk_b1    = (const float*)d_in[3];
    const float* chk_w2    = (const float*)d_in[4];
    const float* chk_b2    = (const float*)d_in[5];
    const float* var_w1    = (const float*)d_in[6];
    const float* var_b1    = (const float*)d_in[7];
    const float* var_w2    = (const float*)d_in[8];
    const float* var_b2    = (const float*)d_in[9];
    const int*   c2v_g     = (const int*)  d_in[11];
    const int*   v2c_g     = (const int*)  d_in[12];

    float* out = (float*)d_out;

    __bf16* v2c  = (__bf16*)d_ws;                           // 12.6 MB
    __bf16* c2v  = v2c + (size_t)EE * BB * 8;               // 12.6 MB
    __bf16* wchk = c2v + (size_t)EE * BB * 8;               // 45.6 MB
    __bf16* wvar = wchk + (size_t)MM * CHK_W_ELEMS;         // 29.4 MB
    float*  sgnT = (float*)(wvar + (size_t)NN * VAR_W_ELEMS); // 512 KB

    prep_fused<<<PREP_GRID, 256, 0, stream>>>(chk_w1, chk_b1, chk_w2, chk_b2,
                                              var_w1, var_b1, var_w2, var_b2,
                                              syndromes, prior_llr,
                                              wchk, wvar, sgnT, v2c);

    for (int t = 0; t < TT; ++t) {
        chk_kernel<<<MM, 256, 0, stream>>>(wchk, sgnT, v2c_g, v2c, c2v);
        var_kernel<<<NN, 256, 0, stream>>>(wvar, c2v_g, prior_llr, c2v, v2c,
                                           out + (size_t)t * BB * NN,
                                           (t == TT - 1) ? 1 : 0);
    }
}